// Round 5
// baseline (160.618 us; speedup 1.0000x reference)
//
#include <hip/hip_runtime.h>

// Guided filter r=5, B=8 C=3 H=W=512 fp32 — SINGLE fused kernel.
// Per 64x16 output tile:
//   P1: load x,y with 2R halo (84x36), vertical 11-sums of (x,y,xy,xx)
//       via register sliding window -> LDS v4[26][84sw]; stash x tile in LDS.
//   P2: horizontal 11-sums (sliding, chunks of 8) -> A,b on 74x26 -> LDS ab2.
//       A,b recomputed in the halo instead of a global ab round-trip.
//   P3: vertical 11-sums of (A,b) -> LDS vab[16][74sw] (aliases v4).
//   P4: horizontal 11-sums + epilogue out = meanA*x + meanb (x from LDS stash).
// Zero-pad conv / N == valid-window sum / (cnt_y*cnt_x), counts analytic;
// A,b outside the image are zero (matches zero-padded second box).
// Swizzles: P1(c)=c+c/4 (float4), Q(c)=c+c/8 (float2); row strides 105*4=420
// (=4 mod 32) and 84*2=168 (=8 mod 32) words keep all phases at the bank floor.

#define R    5
#define TX   64
#define TY   16
#define IMG  512
#define AROWS 26     // TY + 2R
#define ACOLS 74     // TX + 2R
#define XCOLS 84     // TX + 4R
#define PC1  105     // v4 row length (float4), P1(83)=103
#define QC   84      // ab2/vab row length (float2), Q(73)=82
#define XSP  68      // xs row length (float), 272B rows (16B aligned)

#define OFF_AB 43680                  // 26*105*16
#define OFF_XS (OFF_AB + 26*QC*8)    // 43680+17472 = 61152
#define SMEM_TOTAL (OFF_XS + TY*XSP*4)  // 65504 <= 64 KiB

#define P1(c) ((c) + ((c) >> 2))
#define Q(c)  ((c) + ((c) >> 3))

__device__ __forceinline__ float ccnt(int g) {
    int lo = max(g - R, 0), hi = min(g + R, IMG - 1);
    return (float)(hi - lo + 1);
}

__global__ __launch_bounds__(256) void guided_fused(
        const float* __restrict__ x, const float* __restrict__ y,
        float* __restrict__ out) {
    __shared__ __align__(16) unsigned char smem[SMEM_TOTAL];
    float4 (*v4)[PC1] = (float4(*)[PC1])smem;
    float2 (*ab2)[QC] = (float2(*)[QC])(smem + OFF_AB);
    float2 (*vab)[QC] = (float2(*)[QC])smem;          // aliases v4 (dead after P2)
    float  (*xs)[XSP] = (float(*)[XSP])(smem + OFF_XS);

    const int plane = blockIdx.z;
    const int tx0 = blockIdx.x * TX;
    const int ty0 = blockIdx.y * TY;
    const int tid = threadIdx.x;
    const size_t pbase = (size_t)plane * IMG * IMG;
    const float* xp = x + pbase;
    const float* yp = y + pbase;
    const bool interior = (blockIdx.x > 0) & (blockIdx.x < gridDim.x - 1) &
                          (blockIdx.y > 0) & (blockIdx.y < gridDim.y - 1);

    // ---- Phase 1: vertical 11-sums of (x,y,xy,xx) at 84 cols x 26 A,b-rows.
    // 3 row-segments of 9 (27th result discarded), 84 cols -> 252 threads.
    if (tid < 3 * XCOLS) {
        const int seg = tid / XCOLS;          // 0..2
        const int cc  = tid - seg * XCOLS;    // 0..83
        const int r0  = seg * 9;
        const int gx  = tx0 - 2 * R + cc;
        const int gy0 = ty0 - 2 * R + r0;

        float xv[19], yv[19];
        if (interior) {
            const float* xc = xp + (size_t)gy0 * IMG + gx;
            const float* yc = yp + (size_t)gy0 * IMG + gx;
#pragma unroll
            for (int j = 0; j < 19; ++j) {
                xv[j] = xc[(size_t)j * IMG];
                yv[j] = yc[(size_t)j * IMG];
            }
        } else {
            const bool xok = ((unsigned)gx < (unsigned)IMG);
#pragma unroll
            for (int j = 0; j < 19; ++j) {
                int gy = gy0 + j;
                bool ok = xok && ((unsigned)gy < (unsigned)IMG);
                size_t o = (size_t)gy * IMG + gx;
                xv[j] = ok ? xp[o] : 0.f;
                yv[j] = ok ? yp[o] : 0.f;
            }
        }
        // stash the output x-tile: seg 1 holds rows ty0..ty0+15 at j=o+1
        if (seg == 1 && cc >= 10 && cc < 10 + TX) {
#pragma unroll
            for (int o = 0; o < TY; ++o) xs[o][cc - 10] = xv[o + 1];
        }
        float sx = 0.f, sy = 0.f, sxy = 0.f, sxx = 0.f;
#pragma unroll
        for (int j = 0; j < 11; ++j) {
            sx += xv[j]; sy += yv[j];
            sxy += xv[j] * yv[j]; sxx += xv[j] * xv[j];
        }
        v4[r0][P1(cc)] = make_float4(sx, sy, sxy, sxx);
#pragma unroll
        for (int s = 1; s < 9; ++s) {
            const int r = r0 + s;
            float xn = xv[s + 10], yn = yv[s + 10];
            float xo = xv[s - 1],  yo = yv[s - 1];
            sx  += xn - xo;
            sy  += yn - yo;
            sxy += xn * yn - xo * yo;
            sxx += xn * xn - xo * xo;
            if (r < AROWS) v4[r][P1(cc)] = make_float4(sx, sy, sxy, sxx);
        }
    }
    __syncthreads();

    // ---- Phase 2: horizontal 11-sums -> A,b on 74x26. 26 rows x 10 chunks of 8.
#pragma unroll 1
    for (int t = tid; t < AROWS * 10; t += 256) {
        const int r  = t / 10;
        const int ch = t - r * 10;
        const int c0 = ch * 8;
        const int ay = ty0 - R + r;
        float sx = 0.f, sy = 0.f, sxy = 0.f, sxx = 0.f;
#pragma unroll
        for (int d = 0; d < 11; ++d) {
            float4 v = v4[r][P1(c0 + d)];
            sx += v.x; sy += v.y; sxy += v.z; sxx += v.w;
        }
        const float cy = ccnt(ay);
#pragma unroll
        for (int i = 0; i < 8; ++i) {
            const int ac = c0 + i;
            if (ac >= ACOLS) break;
            if (i > 0) {
                float4 a = v4[r][P1(ac + 10)];
                float4 b = v4[r][P1(ac - 1)];
                sx += a.x - b.x; sy += a.y - b.y;
                sxy += a.z - b.z; sxx += a.w - b.w;
            }
            const int ax = tx0 - R + ac;
            float A = 0.f, bb = 0.f;
            if (interior || (((unsigned)ay < (unsigned)IMG) &&
                             ((unsigned)ax < (unsigned)IMG))) {
                float inv = interior ? (1.0f / 121.0f)
                                     : 1.0f / (cy * ccnt(ax));
                float mx = sx * inv, my = sy * inv;
                float cov = sxy * inv - mx * my;
                float var = sxx * inv - mx * mx;
                A = cov / (var + 0.01f);
                bb = my - A * mx;
            }
            ab2[r][Q(ac)] = make_float2(A, bb);
        }
    }
    __syncthreads();

    // ---- Phase 3: vertical 11-sums of (A,b): 74 cols x 2 segments of 8 rows.
    if (tid < 2 * ACOLS) {
        const int hseg = (tid >= ACOLS) ? 1 : 0;
        const int ac = tid - hseg * ACOLS;
        const int r0 = hseg * 8;
        float sa = 0.f, sb = 0.f;
#pragma unroll
        for (int d = 0; d < 11; ++d) {
            float2 v = ab2[r0 + d][Q(ac)];
            sa += v.x; sb += v.y;
        }
        vab[r0][Q(ac)] = make_float2(sa, sb);
#pragma unroll
        for (int s = 1; s < 8; ++s) {
            float2 a = ab2[r0 + s + 10][Q(ac)];
            float2 b = ab2[r0 + s - 1][Q(ac)];
            sa += a.x - b.x; sb += a.y - b.y;
            vab[r0 + s][Q(ac)] = make_float2(sa, sb);
        }
    }
    __syncthreads();

    // ---- Phase 4: horizontal 11-sums + epilogue. 16 rows x 16 chunks of 4.
    {
        const int oy = tid >> 4;
        const int ch = tid & 15;
        const int c0 = ch * 4;
        const int gy = ty0 + oy;
        float sa = 0.f, sb = 0.f;
#pragma unroll
        for (int d = 0; d < 11; ++d) {
            float2 v = vab[oy][Q(c0 + d)];
            sa += v.x; sb += v.y;
        }
        const float cy = ccnt(gy);
        const float4 xv4 = *reinterpret_cast<const float4*>(&xs[oy][c0]);
        const float xv[4] = {xv4.x, xv4.y, xv4.z, xv4.w};
        float res[4];
#pragma unroll
        for (int i = 0; i < 4; ++i) {
            const int l = c0 + i;
            if (i > 0) {
                float2 a = vab[oy][Q(l + 10)];
                float2 b = vab[oy][Q(l - 1)];
                sa += a.x - b.x; sb += a.y - b.y;
            }
            float inv = interior ? (1.0f / 121.0f)
                                 : 1.0f / (cy * ccnt(tx0 + l));
            res[i] = (sa * inv) * xv[i] + (sb * inv);
        }
        *reinterpret_cast<float4*>(&out[pbase + (size_t)gy * IMG + tx0 + c0]) =
            make_float4(res[0], res[1], res[2], res[3]);
    }
}

extern "C" void kernel_launch(void* const* d_in, const int* in_sizes, int n_in,
                              void* d_out, int out_size, void* d_ws, size_t ws_size,
                              hipStream_t stream) {
    const float* x = (const float*)d_in[0];
    const float* y = (const float*)d_in[1];
    float* out = (float*)d_out;

    const int planes = in_sizes[0] / (IMG * IMG);  // 24

    dim3 grid(IMG / TX, IMG / TY, planes);
    guided_fused<<<grid, 256, 0, stream>>>(x, y, out);
}

// Round 6
// 135.524 us; speedup vs baseline: 1.1852x; 1.1852x over previous
//
#include <hip/hip_runtime.h>

// Guided filter r=5, B=8 C=3 H=W=512 fp32 — single fused kernel, round 6.
// Per 64x14 output tile:
//   P1: load x,y with 2R halo, vertical 11-sums of (x,y,xy,xx) via register
//       sliding window -> LDS v4[24][97sw] (float4).
//   P2: horizontal 11-sums (width-4 chunks, conflict-free mapping) -> A,b on
//       74x24 -> LDS ab2[24][83sw] (float2).
//   P3: vertical 11-sums of (A,b) -> vab[14][83sw] (aliases v4).
//   P4: horizontal 11-sums + epilogue out = meanA*x + meanb (x re-read global).
// Swizzle PB(c)=c+(c>>3). Bank check (words mod 32):
//   P1 writes: lanes=consec cc, 4*PB(cc) covers 8 groups twice/16 lanes -> 2/bank.
//   P2 reads:  16-lane group same r, c0=4m: 4*PB(4m)=16m+4(m>>1): each residue
//              exactly 2x over m=0..15 -> 2/bank. Row stride 97*4=388=4 mod 32.
//   P3/P4 b64: consec ac / c0=4ch -> <=2-3 words/bank.
// LDS 53,184 B -> 3 blocks/CU (was 65,504 -> 2).

#define R    5
#define TX   64
#define TY   14
#define IMG  512
#define AROWS (TY + 2 * R)   // 24
#define ACOLS (TX + 2 * R)   // 74
#define XCOLS (TX + 4 * R)   // 84
#define V4STR 97             // float4 row stride, PB(83)=93
#define ABSTR 83             // float2 row stride, PB(73)=82
#define OFF_AB (AROWS * V4STR * 16)            // 37248
#define SMEM_TOTAL (OFF_AB + AROWS * ABSTR * 8) // 53184

#define PB(c) ((c) + ((c) >> 3))

__device__ __forceinline__ float ccnt(int g) {
    int lo = max(g - R, 0), hi = min(g + R, IMG - 1);
    return (float)(hi - lo + 1);
}

__device__ __forceinline__ void p2_chunk(
        int r, int m, int tx0, int ty0, bool interior,
        const float4 (*v4)[V4STR], float2 (*ab2)[ABSTR]) {
    const int c0 = 4 * m;
    float sx = 0.f, sy = 0.f, sxy = 0.f, sxx = 0.f;
#pragma unroll
    for (int d = 0; d < 11; ++d) {
        float4 v = v4[r][PB(c0 + d)];
        sx += v.x; sy += v.y; sxy += v.z; sxx += v.w;
    }
    const int ay = ty0 - R + r;
    const float cy = ccnt(ay);
#pragma unroll
    for (int i = 0; i < 4; ++i) {
        const int ac = c0 + i;
        if (ac >= ACOLS) break;
        if (i > 0) {
            float4 a = v4[r][PB(ac + 10)];
            float4 b = v4[r][PB(ac - 1)];
            sx += a.x - b.x; sy += a.y - b.y;
            sxy += a.z - b.z; sxx += a.w - b.w;
        }
        const int ax = tx0 - R + ac;
        float A = 0.f, bb = 0.f;
        if (interior || (((unsigned)ay < (unsigned)IMG) &&
                         ((unsigned)ax < (unsigned)IMG))) {
            float inv = interior ? (1.0f / 121.0f)
                                 : __builtin_amdgcn_rcpf(cy * ccnt(ax));
            float mx = sx * inv, my = sy * inv;
            float cov = sxy * inv - mx * my;
            float var = sxx * inv - mx * mx;
            A = cov * __builtin_amdgcn_rcpf(var + 0.01f);
            bb = my - A * mx;
        }
        ab2[r][PB(ac)] = make_float2(A, bb);
    }
}

__global__ __launch_bounds__(256, 3) void guided_fused(
        const float* __restrict__ x, const float* __restrict__ y,
        float* __restrict__ out) {
    __shared__ __align__(16) unsigned char smem[SMEM_TOTAL];
    float4 (*v4)[V4STR] = (float4(*)[V4STR])smem;
    float2 (*ab2)[ABSTR] = (float2(*)[ABSTR])(smem + OFF_AB);
    float2 (*vab)[ABSTR] = (float2(*)[ABSTR])smem;   // aliases v4 (dead after P2)

    const int plane = blockIdx.z;
    const int tx0 = blockIdx.x * TX;
    const int ty0 = blockIdx.y * TY;
    const int tid = threadIdx.x;
    const size_t pbase = (size_t)plane * IMG * IMG;
    const float* xp = x + pbase;
    const float* yp = y + pbase;
    // interior: the full 2R halo of raw rows/cols is inside the image
    const bool interior = (tx0 >= 2 * R) && (tx0 + TX + 2 * R - 1 < IMG) &&
                          (ty0 >= 2 * R) && (ty0 + TY + 2 * R - 1 < IMG);

    // ---- P1: vertical 11-sums at 84 cols x 24 A,b-rows. 3 segs x 8 rows.
    if (tid < 3 * XCOLS) {
        const int seg = tid / XCOLS;
        const int cc  = tid - seg * XCOLS;
        const int r0  = seg * 8;
        const int gx  = tx0 - 2 * R + cc;
        const int gy0 = ty0 - 2 * R + r0;

        float xv[18], yv[18];
        if (interior) {
            const float* xc = xp + (size_t)gy0 * IMG + gx;
            const float* yc = yp + (size_t)gy0 * IMG + gx;
#pragma unroll
            for (int j = 0; j < 18; ++j) {
                xv[j] = xc[(size_t)j * IMG];
                yv[j] = yc[(size_t)j * IMG];
            }
        } else {
            const bool xok = ((unsigned)gx < (unsigned)IMG);
#pragma unroll
            for (int j = 0; j < 18; ++j) {
                int gy = gy0 + j;
                bool ok = xok && ((unsigned)gy < (unsigned)IMG);
                size_t o = (size_t)gy * IMG + gx;
                xv[j] = ok ? xp[o] : 0.f;
                yv[j] = ok ? yp[o] : 0.f;
            }
        }
        float sx = 0.f, sy = 0.f, sxy = 0.f, sxx = 0.f;
#pragma unroll
        for (int j = 0; j < 11; ++j) {
            sx += xv[j]; sy += yv[j];
            sxy += xv[j] * yv[j]; sxx += xv[j] * xv[j];
        }
        v4[r0][PB(cc)] = make_float4(sx, sy, sxy, sxx);
#pragma unroll
        for (int s = 1; s < 8; ++s) {
            float xn = xv[s + 10], yn = yv[s + 10];
            float xo = xv[s - 1],  yo = yv[s - 1];
            sx  += xn - xo;
            sy  += yn - yo;
            sxy += xn * yn - xo * yo;
            sxx += xn * xn - xo * xo;
            v4[r0 + s][PB(cc)] = make_float4(sx, sy, sxy, sxx);
        }
    }
    __syncthreads();

    // ---- P2: horizontal 11-sums -> A,b on 74x24. 24 rows x 19 width-4 chunks.
    // pass A: rows 0-15, chunks 0-15 (16-lane groups: same r, consec m -> free)
    { p2_chunk(tid >> 4, tid & 15, tx0, ty0, interior, v4, ab2); }
    // pass B: rows 16-23, chunks 0-15
    if (tid < 128) p2_chunk(16 + (tid >> 4), tid & 15, tx0, ty0, interior, v4, ab2);
    // pass C: chunks 16-18, rows 0-23 (16-lane groups: same m, consec r -> free)
    if (tid < 72)  p2_chunk(tid % 24, 16 + tid / 24, tx0, ty0, interior, v4, ab2);
    __syncthreads();

    // ---- P3: vertical 11-sums of (A,b): 74 cols x 2 segs of 7 rows.
    if (tid < 2 * ACOLS) {
        const int hs = (tid >= ACOLS) ? 1 : 0;
        const int ac = tid - hs * ACOLS;
        const int r0 = hs * 7;
        float sa = 0.f, sb = 0.f;
#pragma unroll
        for (int d = 0; d < 11; ++d) {
            float2 v = ab2[r0 + d][PB(ac)];
            sa += v.x; sb += v.y;
        }
        vab[r0][PB(ac)] = make_float2(sa, sb);
#pragma unroll
        for (int s = 1; s < 7; ++s) {
            float2 a = ab2[r0 + s + 10][PB(ac)];
            float2 b = ab2[r0 + s - 1][PB(ac)];
            sa += a.x - b.x; sb += a.y - b.y;
            vab[r0 + s][PB(ac)] = make_float2(sa, sb);
        }
    }
    __syncthreads();

    // ---- P4: horizontal 11-sums + epilogue. 14 rows x 16 width-4 chunks.
    if (tid < TY * 16) {
        const int oy = tid >> 4;
        const int ch = tid & 15;
        const int c0 = 4 * ch;
        const int gy = ty0 + oy;
        if (gy < IMG) {
            float sa = 0.f, sb = 0.f;
#pragma unroll
            for (int d = 0; d < 11; ++d) {
                float2 v = vab[oy][PB(c0 + d)];
                sa += v.x; sb += v.y;
            }
            const float cy = ccnt(gy);
            const size_t obase = (size_t)gy * IMG + tx0 + c0;
            const float4 xv4 = *reinterpret_cast<const float4*>(&xp[obase]);
            const float xv[4] = {xv4.x, xv4.y, xv4.z, xv4.w};
            float res[4];
#pragma unroll
            for (int i = 0; i < 4; ++i) {
                const int l = c0 + i;
                if (i > 0) {
                    float2 a = vab[oy][PB(l + 10)];
                    float2 b = vab[oy][PB(l - 1)];
                    sa += a.x - b.x; sb += a.y - b.y;
                }
                float inv = interior ? (1.0f / 121.0f)
                                     : __builtin_amdgcn_rcpf(cy * ccnt(tx0 + l));
                res[i] = (sa * inv) * xv[i] + (sb * inv);
            }
            *reinterpret_cast<float4*>(&out[pbase + obase]) =
                make_float4(res[0], res[1], res[2], res[3]);
        }
    }
}

extern "C" void kernel_launch(void* const* d_in, const int* in_sizes, int n_in,
                              void* d_out, int out_size, void* d_ws, size_t ws_size,
                              hipStream_t stream) {
    const float* x = (const float*)d_in[0];
    const float* y = (const float*)d_in[1];
    float* out = (float*)d_out;

    const int planes = in_sizes[0] / (IMG * IMG);  // 24

    dim3 grid(IMG / TX, (IMG + TY - 1) / TY, planes);  // 8 x 37 x 24
    guided_fused<<<grid, 256, 0, stream>>>(x, y, out);
}

// Round 7
// 124.312 us; speedup vs baseline: 1.2921x; 1.0902x over previous
//
#include <hip/hip_runtime.h>

// Guided filter r=5, B=8 C=3 H=W=512 fp32 — single fused kernel, round 7.
// Per 64x14 output tile:
//   P1: load x,y with 2R halo, vertical 11-sums of (x,y,xy,xx) via register
//       sliding window -> LDS v4[24][97sw] (float4).
//   P2: horizontal 11-sums, width-8 chunks with a 10-deep float4 REGISTER RING
//       (trailing edge from registers, only leading edge read from LDS:
//       18 b128/thread for 8 outputs vs 4.25/output before) -> A,b -> ab2.
//   P3: vertical 11-sums of (A,b), register ring (17 b64 reads) -> vab (aliases v4).
//   P4: horizontal 11-sums + epilogue, register ring (14 b64 reads);
//       out = meanA*x + meanb, x re-read from global (L3-hot, coalesced).
// Bank floors (words mod 32), PB(c)=c+(c>>3), V4STR=97 (388w==4), ABSTR=83 (166w==6):
//   P1 writes: consec cc, 4*PB(cc) -> {0,4,..,28} x2 -> floor.
//   P2 reads:  16-lane group same chunk, consec r -> const + 4r -> floor.
//   P2 writes: same col, consec r -> 6r mod 32 all distinct -> floor.
//   P3/P4: consec ac / c0=4ch b64 -> <=2-3 words/bank.
// LDS 53,184 B -> 3 blocks/CU.

#define R    5
#define TX   64
#define TY   14
#define IMG  512
#define AROWS (TY + 2 * R)   // 24
#define ACOLS (TX + 2 * R)   // 74
#define XCOLS (TX + 4 * R)   // 84
#define V4STR 97             // float4 row stride, PB(83)=93
#define ABSTR 83             // float2 row stride, PB(73)=82
#define OFF_AB (AROWS * V4STR * 16)             // 37248
#define SMEM_TOTAL (OFF_AB + AROWS * ABSTR * 8) // 53184

#define PB(c) ((c) + ((c) >> 3))

__device__ __forceinline__ float ccnt(int g) {
    int lo = max(g - R, 0), hi = min(g + R, IMG - 1);
    return (float)(hi - lo + 1);
}

__global__ __launch_bounds__(256, 3) void guided_fused(
        const float* __restrict__ x, const float* __restrict__ y,
        float* __restrict__ out) {
    __shared__ __align__(16) unsigned char smem[SMEM_TOTAL];
    float4 (*v4)[V4STR] = (float4(*)[V4STR])smem;
    float2 (*ab2)[ABSTR] = (float2(*)[ABSTR])(smem + OFF_AB);
    float2 (*vab)[ABSTR] = (float2(*)[ABSTR])smem;   // aliases v4 (dead after P2)

    const int plane = blockIdx.z;
    const int tx0 = blockIdx.x * TX;
    const int ty0 = blockIdx.y * TY;
    const int tid = threadIdx.x;
    const size_t pbase = (size_t)plane * IMG * IMG;
    const float* xp = x + pbase;
    const float* yp = y + pbase;
    const bool interior = (tx0 >= 2 * R) && (tx0 + TX + 2 * R - 1 < IMG) &&
                          (ty0 >= 2 * R) && (ty0 + TY + 2 * R - 1 < IMG);

    // ---- P1: vertical 11-sums at 84 cols x 24 A,b-rows. 3 segs x 8 rows.
    if (tid < 3 * XCOLS) {
        const int seg = tid / XCOLS;
        const int cc  = tid - seg * XCOLS;
        const int r0  = seg * 8;
        const int gx  = tx0 - 2 * R + cc;
        const int gy0 = ty0 - 2 * R + r0;

        float xv[18], yv[18];
        if (interior) {
            const float* xc = xp + (size_t)gy0 * IMG + gx;
            const float* yc = yp + (size_t)gy0 * IMG + gx;
#pragma unroll
            for (int j = 0; j < 18; ++j) {
                xv[j] = xc[(size_t)j * IMG];
                yv[j] = yc[(size_t)j * IMG];
            }
        } else {
            const bool xok = ((unsigned)gx < (unsigned)IMG);
#pragma unroll
            for (int j = 0; j < 18; ++j) {
                int gy = gy0 + j;
                bool ok = xok && ((unsigned)gy < (unsigned)IMG);
                size_t o = (size_t)gy * IMG + gx;
                xv[j] = ok ? xp[o] : 0.f;
                yv[j] = ok ? yp[o] : 0.f;
            }
        }
        float sx = 0.f, sy = 0.f, sxy = 0.f, sxx = 0.f;
#pragma unroll
        for (int j = 0; j < 11; ++j) {
            sx += xv[j]; sy += yv[j];
            sxy += xv[j] * yv[j]; sxx += xv[j] * xv[j];
        }
        v4[r0][PB(cc)] = make_float4(sx, sy, sxy, sxx);
#pragma unroll
        for (int s = 1; s < 8; ++s) {
            float xn = xv[s + 10], yn = yv[s + 10];
            float xo = xv[s - 1],  yo = yv[s - 1];
            sx  += xn - xo;
            sy  += yn - yo;
            sxy += xn * yn - xo * yo;
            sxx += xn * xn - xo * xo;
            v4[r0 + s][PB(cc)] = make_float4(sx, sy, sxy, sxx);
        }
    }
    __syncthreads();

    // ---- P2: horizontal 11-sums -> A,b on 74x24. 240 threads:
    // chunk ch = tid/24 (0..9, width 8), row r = tid%24. Register ring.
    if (tid < 240) {
        const int ch = tid / 24;
        const int r  = tid - ch * 24;
        const int c0 = 8 * ch;
        const int nout = min(8, ACOLS - c0);   // 8, or 2 for ch=9

        float4 ring[10];
#pragma unroll
        for (int d = 0; d < 10; ++d) ring[d] = v4[r][PB(c0 + d)];
        float sx = 0.f, sy = 0.f, sxy = 0.f, sxx = 0.f;
#pragma unroll
        for (int d = 0; d < 10; ++d) {
            sx += ring[d].x; sy += ring[d].y;
            sxy += ring[d].z; sxx += ring[d].w;
        }
        const int ay = ty0 - R + r;
        const float cy = ccnt(ay);
        const bool ayok = ((unsigned)ay < (unsigned)IMG);
#pragma unroll
        for (int i = 0; i < 8; ++i) {
            if (i < nout) {
                float4 lead = v4[r][PB(c0 + 10 + i)];
                sx += lead.x; sy += lead.y; sxy += lead.z; sxx += lead.w;
                if (i > 0) {
                    float4 o = ring[(i > 0) ? (i - 1) : 0];
                    sx -= o.x; sy -= o.y; sxy -= o.z; sxx -= o.w;
                }
                const int ac = c0 + i;
                const int ax = tx0 - R + ac;
                float A = 0.f, bb = 0.f;
                if (interior || (ayok && ((unsigned)ax < (unsigned)IMG))) {
                    float inv = interior ? (1.0f / 121.0f)
                                         : __builtin_amdgcn_rcpf(cy * ccnt(ax));
                    float mx = sx * inv, my = sy * inv;
                    float cov = sxy * inv - mx * my;
                    float var = sxx * inv - mx * mx;
                    A = cov * __builtin_amdgcn_rcpf(var + 0.01f);
                    bb = my - A * mx;
                }
                ab2[r][PB(ac)] = make_float2(A, bb);
            }
        }
    }
    __syncthreads();

    // ---- P3: vertical 11-sums of (A,b): 74 cols x 2 segs of 7 rows. Ring.
    if (tid < 2 * ACOLS) {
        const int seg = (tid >= ACOLS) ? 1 : 0;
        const int ac = tid - seg * ACOLS;
        const int r0 = seg * 7;
        float2 ring[10];
#pragma unroll
        for (int d = 0; d < 10; ++d) ring[d] = ab2[r0 + d][PB(ac)];
        float sa = 0.f, sb = 0.f;
#pragma unroll
        for (int d = 0; d < 10; ++d) { sa += ring[d].x; sb += ring[d].y; }
#pragma unroll
        for (int s = 0; s < 7; ++s) {
            float2 lead = ab2[r0 + 10 + s][PB(ac)];
            sa += lead.x; sb += lead.y;
            if (s > 0) {
                float2 o = ring[(s > 0) ? (s - 1) : 0];
                sa -= o.x; sb -= o.y;
            }
            vab[r0 + s][PB(ac)] = make_float2(sa, sb);
        }
    }
    __syncthreads();

    // ---- P4: horizontal 11-sums + epilogue. 14 rows x 16 width-4 chunks. Ring.
    if (tid < TY * 16) {
        const int oy = tid >> 4;
        const int ch = tid & 15;
        const int c0 = 4 * ch;
        const int gy = ty0 + oy;
        if (gy < IMG) {
            float2 ring[10];
#pragma unroll
            for (int d = 0; d < 10; ++d) ring[d] = vab[oy][PB(c0 + d)];
            float sa = 0.f, sb = 0.f;
#pragma unroll
            for (int d = 0; d < 10; ++d) { sa += ring[d].x; sb += ring[d].y; }
            const float cy = ccnt(gy);
            const size_t obase = (size_t)gy * IMG + tx0 + c0;
            const float4 xv4 = *reinterpret_cast<const float4*>(&xp[obase]);
            const float xv[4] = {xv4.x, xv4.y, xv4.z, xv4.w};
            float res[4];
#pragma unroll
            for (int i = 0; i < 4; ++i) {
                float2 lead = vab[oy][PB(c0 + 10 + i)];
                sa += lead.x; sb += lead.y;
                if (i > 0) {
                    float2 o = ring[(i > 0) ? (i - 1) : 0];
                    sa -= o.x; sb -= o.y;
                }
                float inv = interior ? (1.0f / 121.0f)
                                     : __builtin_amdgcn_rcpf(cy * ccnt(tx0 + c0 + i));
                res[i] = (sa * inv) * xv[i] + (sb * inv);
            }
            *reinterpret_cast<float4*>(&out[pbase + obase]) =
                make_float4(res[0], res[1], res[2], res[3]);
        }
    }
}

extern "C" void kernel_launch(void* const* d_in, const int* in_sizes, int n_in,
                              void* d_out, int out_size, void* d_ws, size_t ws_size,
                              hipStream_t stream) {
    const float* x = (const float*)d_in[0];
    const float* y = (const float*)d_in[1];
    float* out = (float*)d_out;

    const int planes = in_sizes[0] / (IMG * IMG);  // 24

    dim3 grid(IMG / TX, (IMG + TY - 1) / TY, planes);  // 8 x 37 x 24
    guided_fused<<<grid, 256, 0, stream>>>(x, y, out);
}